// Round 10
// baseline (334.305 us; speedup 1.0000x reference)
//
#include <hip/hip_runtime.h>

#define N_TOTAL    150100
#define NUM_USERS  100000
#define DIM        64
#define BSHIFT     8                                   // 256 rows per bucket
#define BROWS      (1 << BSHIFT)
#define NBUK       ((N_TOTAL + BROWS - 1) / BROWS)     // 587
#define EPB        4096                                // edges per build block
#define CAP        5632                                // bucket capacity (mu=5116, sigma=72)
#define RSP        260                                 // row_start pitch (257 used)

// ---------- bf16 helpers (round-to-nearest-even, pack 2 per uint) ----------
__device__ __forceinline__ unsigned bfr(float f) {
    unsigned u = __float_as_uint(f);
    return (u + 0x7FFFu + ((u >> 16) & 1u)) >> 16;
}
__device__ __forceinline__ unsigned pack2(float lo, float hi) {
    return bfr(lo) | (bfr(hi) << 16);
}
__device__ __forceinline__ float unlo(unsigned w) { return __uint_as_float(w << 16); }
__device__ __forceinline__ float unhi(unsigned w) { return __uint_as_float(w & 0xFFFF0000u); }

// fp32 table -> bf16 table (uint2 = 4 bf16)
__global__ void convert_emb(const float4* __restrict__ in4,
                            uint2* __restrict__ outh, int n4) {
    int t = blockIdx.x * blockDim.x + threadIdx.x;
    if (t >= n4) return;
    float4 f = in4[t];
    outh[t] = make_uint2(pack2(f.x, f.y), pack2(f.z, f.w));
}

// ---------- build stage 1: LDS-staged bucket fill, coalesced run writes ------
// LDS budget 49 KB -> 3 blocks/CU (vs r9's 57 KB / 2 blocks).
__global__ void __launch_bounds__(256) fill_buckets(
        const int* __restrict__ rows, const int* __restrict__ cols,
        const float* __restrict__ vals, int n_edges,
        int* __restrict__ gcount, int2* __restrict__ pair) {
    __shared__ int2  buf[EPB];       // 32 KB (sorted-by-bucket staging)
    __shared__ short tgtb[EPB];      // 8 KB (bucket id per sorted slot)
    __shared__ int   hist[NBUK];
    __shared__ int   pref[NBUK];
    __shared__ int   loc[NBUK];
    __shared__ int   scan[256];
    const int tid = threadIdx.x;
    const int base = blockIdx.x * EPB;
    int end = base + EPB; if (end > n_edges) end = n_edges;
    const int cnt = end - base;

    for (int i = tid; i < NBUK; i += 256) hist[i] = 0;
    __syncthreads();
    // pass 1: LDS histogram of bucket ids
    for (int i = base + tid; i < end; i += 256)
        atomicAdd(&hist[rows[i] >> BSHIFT], 1);
    __syncthreads();
    // prefix scan over NBUK bins (3 bins/thread + block scan)
    const int t0 = tid * 3;
    int t1 = t0 + 3; if (t1 > NBUK) t1 = NBUK;
    int s = 0;
    for (int i = t0; i < t1; ++i) s += hist[i];
    scan[tid] = s;
    __syncthreads();
    for (int off = 1; off < 256; off <<= 1) {
        int v = 0;
        if (tid >= off) v = scan[tid - off];
        __syncthreads();
        if (tid >= off) scan[tid] += v;
        __syncthreads();
    }
    int run = (tid == 0) ? 0 : scan[tid - 1];
    for (int i = t0; i < t1; ++i) { int h = hist[i]; pref[i] = run; run += h; }
    __syncthreads();
    // global run reservations (1 atomic per nonzero (block,bucket))
    for (int b = tid; b < NBUK; b += 256) {
        int h = hist[b];
        loc[b] = h ? (b * CAP + atomicAdd(&gcount[b], h)) : 0;
        hist[b] = pref[b];           // reuse as LDS cursor
    }
    __syncthreads();
    // pass 2: re-read edges (L2-hot), scatter into LDS sorted-by-bucket order
    for (int i = base + tid; i < end; i += 256) {
        int r = rows[i];
        int b = r >> BSHIFT;
        int pos = atomicAdd(&hist[b], 1);
        buf[pos] = make_int2(((r & (BROWS - 1)) << 18) | cols[i],
                             __float_as_int(vals[i]));
        tgtb[pos] = (short)b;
    }
    __syncthreads();
    // pass 3: coalesced run writes (target recomputed from bucket id)
    for (int i = tid; i < cnt; i += 256) {
        int b = tgtb[i];
        int t = loc[b] + (i - pref[b]);
        if (t < NBUK * CAP)          // statistically unreachable overflow guard
            pair[t] = buf[i];
    }
}

// ---------- build stage 2: per-bucket counting sort, ping-pong (no LDS buf) --
// pairA (bucket-grouped) -> pairB (row-sorted). LDS = 2 KB -> high occupancy.
__global__ void __launch_bounds__(256) bucket_sort(
        const int2* __restrict__ pairA,
        int2* __restrict__ pairB,
        const int* __restrict__ gcount,
        int* __restrict__ rs) {
    __shared__ int hist[BROWS];
    __shared__ int pref[BROWS];
    const int tid = threadIdx.x;
    const int b = blockIdx.x;
    const int k0 = b * CAP;
    int cnt = gcount[b]; if (cnt > CAP) cnt = CAP;

    hist[tid] = 0;
    __syncthreads();
    // pass 1: histogram over local rows (coalesced global read)
    for (int i = tid; i < cnt; i += 256)
        atomicAdd(&hist[pairA[k0 + i].x >> 18], 1);
    __syncthreads();
    pref[tid] = hist[tid];
    __syncthreads();
    #pragma unroll
    for (int off = 1; off < BROWS; off <<= 1) {
        int v = 0;
        if (tid >= off) v = pref[tid - off];
        __syncthreads();
        if (tid >= off) pref[tid] += v;
        __syncthreads();
    }
    const int rbase = b << BSHIFT;
    int nrow = N_TOTAL - rbase; if (nrow > BROWS) nrow = BROWS;
    if (tid < nrow) {
        int ex = pref[tid] - hist[tid];
        rs[b * RSP + tid] = k0 + ex;
        hist[tid] = ex;                  // reuse as local cursor
    }
    if (tid == 0) rs[b * RSP + nrow] = k0 + cnt;
    __syncthreads();
    // pass 2: re-read (L2-hot), scatter into pairB within the bucket window
    for (int i = tid; i < cnt; i += 256) {
        int2 e = pairA[k0 + i];
        int rl = e.x >> 18;
        int pos = atomicAdd(&hist[rl], 1);
        pairB[k0 + pos] = make_int2(e.x & 0x3FFFF, e.y);   // strip row bits
    }
}

// ---------- propagation: bf16 gather, 16 lanes/row, 4-edge load batching ----

#define SPMM_BODY(C, V)                                                        \
    do {                                                                       \
        uint2 w = embh[(size_t)(C) * 16 + sl];                                 \
        s.x += (V) * unlo(w.x); s.y += (V) * unhi(w.x);                        \
        s.z += (V) * unlo(w.y); s.w += (V) * unhi(w.y);                        \
    } while (0)

__global__ void spmm_bf16(const uint2* __restrict__ embh,
                          const int* __restrict__ rs,
                          const int2* __restrict__ pair,
                          uint2* __restrict__ outh) {
    int t = blockIdx.x * blockDim.x + threadIdx.x;
    int r = t >> 4;
    int sl = t & 15;
    int lane = threadIdx.x & 63;
    int subbase = lane & 48;
    if (r >= N_TOTAL) return;
    const int* rsb = rs + (r >> BSHIFT) * RSP + (r & (BROWS - 1));
    int k0 = rsb[0], k1 = rsb[1];
    float4 s = make_float4(0.f, 0.f, 0.f, 0.f);
    for (int kb = k0; kb < k1; kb += 16) {
        int cnt = k1 - kb; if (cnt > 16) cnt = 16;
        int2 pr = (sl < cnt) ? pair[kb + sl] : make_int2(0, 0);
        int j = 0;
        for (; j + 4 <= cnt; j += 4) {
            int   c0 = __shfl(pr.x, subbase + j + 0, 64);
            int   c1 = __shfl(pr.x, subbase + j + 1, 64);
            int   c2 = __shfl(pr.x, subbase + j + 2, 64);
            int   c3 = __shfl(pr.x, subbase + j + 3, 64);
            float v0 = __int_as_float(__shfl(pr.y, subbase + j + 0, 64));
            float v1 = __int_as_float(__shfl(pr.y, subbase + j + 1, 64));
            float v2 = __int_as_float(__shfl(pr.y, subbase + j + 2, 64));
            float v3 = __int_as_float(__shfl(pr.y, subbase + j + 3, 64));
            uint2 w0 = embh[(size_t)c0 * 16 + sl];
            uint2 w1 = embh[(size_t)c1 * 16 + sl];
            uint2 w2 = embh[(size_t)c2 * 16 + sl];
            uint2 w3 = embh[(size_t)c3 * 16 + sl];
            s.x += v0 * unlo(w0.x); s.y += v0 * unhi(w0.x);
            s.z += v0 * unlo(w0.y); s.w += v0 * unhi(w0.y);
            s.x += v1 * unlo(w1.x); s.y += v1 * unhi(w1.x);
            s.z += v1 * unlo(w1.y); s.w += v1 * unhi(w1.y);
            s.x += v2 * unlo(w2.x); s.y += v2 * unhi(w2.x);
            s.z += v2 * unlo(w2.y); s.w += v2 * unhi(w2.y);
            s.x += v3 * unlo(w3.x); s.y += v3 * unhi(w3.x);
            s.z += v3 * unlo(w3.y); s.w += v3 * unhi(w3.y);
        }
        for (; j < cnt; ++j) {
            int   c = __shfl(pr.x, subbase + j, 64);
            float v = __int_as_float(__shfl(pr.y, subbase + j, 64));
            SPMM_BODY(c, v);
        }
    }
    outh[(size_t)r * 16 + sl] = make_uint2(pack2(s.x, s.y), pack2(s.z, s.w));
}

// Layer-3 shortcut: row-sum only at the 2*batch gathered rows, += into fp32 acc
__global__ void spmm_rows_acc(const uint2* __restrict__ embh,
                              const int* __restrict__ rs,
                              const int2* __restrict__ pair,
                              const int* __restrict__ user_ids,
                              const int* __restrict__ item_ids,
                              float4* __restrict__ acc4, int batch) {
    int t = blockIdx.x * blockDim.x + threadIdx.x;
    int b = t >> 4;
    int sl = t & 15;
    int lane = threadIdx.x & 63;
    int subbase = lane & 48;
    if (b >= 2 * batch) return;
    int r = (b < batch) ? user_ids[b] : (NUM_USERS + item_ids[b - batch]);
    const int* rsb = rs + (r >> BSHIFT) * RSP + (r & (BROWS - 1));
    int k0 = rsb[0], k1 = rsb[1];
    float4 s = make_float4(0.f, 0.f, 0.f, 0.f);
    for (int kb = k0; kb < k1; kb += 16) {
        int cnt = k1 - kb; if (cnt > 16) cnt = 16;
        int2 pr = (sl < cnt) ? pair[kb + sl] : make_int2(0, 0);
        for (int j = 0; j < cnt; ++j) {
            int   c = __shfl(pr.x, subbase + j, 64);
            float v = __int_as_float(__shfl(pr.y, subbase + j, 64));
            SPMM_BODY(c, v);
        }
    }
    float4 a = acc4[(size_t)b * 16 + sl];
    a.x += s.x; a.y += s.y; a.z += s.z; a.w += s.w;
    acc4[(size_t)b * 16 + sl] = a;
}

// ---------- readout ----------

__global__ void gather_init(const float4* __restrict__ emb4,
                            const int* __restrict__ user_ids,
                            const int* __restrict__ item_ids,
                            float4* __restrict__ acc4, int batch) {
    int t = blockIdx.x * blockDim.x + threadIdx.x;
    int b = t >> 4, sl = t & 15;
    if (b >= 2 * batch) return;
    int row = (b < batch) ? user_ids[b] : (NUM_USERS + item_ids[b - batch]);
    acc4[(size_t)b * 16 + sl] = emb4[(size_t)row * 16 + sl];
}

// acc(fp32) += bf16 table row
__global__ void acc_gather_add_h(const uint2* __restrict__ embh,
                                 const int* __restrict__ user_ids,
                                 const int* __restrict__ item_ids,
                                 float4* __restrict__ acc4, int batch) {
    int t = blockIdx.x * blockDim.x + threadIdx.x;
    int b = t >> 4, sl = t & 15;
    if (b >= 2 * batch) return;
    int row = (b < batch) ? user_ids[b] : (NUM_USERS + item_ids[b - batch]);
    uint2 w = embh[(size_t)row * 16 + sl];
    float4 a = acc4[(size_t)b * 16 + sl];
    a.x += unlo(w.x); a.y += unhi(w.x); a.z += unlo(w.y); a.w += unhi(w.y);
    acc4[(size_t)b * 16 + sl] = a;
}

__global__ void final_dot(const float4* __restrict__ acc4,
                          float* __restrict__ out, int batch) {
    int t = blockIdx.x * blockDim.x + threadIdx.x;
    int b = t >> 4, sl = t & 15;
    if (b >= batch) return;
    float4 u = acc4[(size_t)b * 16 + sl];
    float4 v = acc4[(size_t)(b + batch) * 16 + sl];
    float s = u.x * v.x + u.y * v.y + u.z * v.z + u.w * v.w;
    #pragma unroll
    for (int off = 8; off > 0; off >>= 1) s += __shfl_down(s, off, 64);
    if (sl == 0) out[b] = s * (1.0f / 16.0f);
}

// ---------- launch ----------

static inline size_t align256(size_t x) { return (x + 255) & ~(size_t)255; }

extern "C" void kernel_launch(void* const* d_in, const int* in_sizes, int n_in,
                              void* d_out, int out_size, void* d_ws, size_t ws_size,
                              hipStream_t stream) {
    const float* node_emb = (const float*)d_in[0];
    const float* adj_val  = (const float*)d_in[1];
    const int*   adj_row  = (const int*)d_in[2];
    const int*   adj_col  = (const int*)d_in[3];
    const int*   user_ids = (const int*)d_in[4];
    const int*   item_ids = (const int*)d_in[5];
    float* out = (float*)d_out;

    const int n_edges = in_sizes[1];
    const int batch   = in_sizes[4];

    const size_t embh_bytes = (size_t)N_TOTAL * DIM * 2;   // bf16 table

    char* p = (char*)d_ws;
    size_t off = 0;
    uint2* emb0h  = (uint2*)(p + off); off = align256(off + embh_bytes);
    uint2* bufAh  = (uint2*)(p + off); off = align256(off + embh_bytes);
    uint2* bufBh  = (uint2*)(p + off); off = align256(off + embh_bytes);
    float* acc    = (float*)(p + off); off = align256(off + (size_t)2 * batch * DIM * sizeof(float));
    int* gcount   = (int*)(p + off);   off = align256(off + (size_t)NBUK * sizeof(int));
    int* rs       = (int*)(p + off);   off = align256(off + (size_t)NBUK * RSP * sizeof(int));
    int2* pairA   = (int2*)(p + off);  off = align256(off + (size_t)NBUK * CAP * sizeof(int2));
    int2* pairB   = (int2*)(p + off);  off = align256(off + (size_t)NBUK * CAP * sizeof(int2));
    (void)ws_size;

    const int nbf = (n_edges + EPB - 1) / EPB;   // 733

    // --- build ---
    hipMemsetAsync(gcount, 0, (size_t)NBUK * sizeof(int), stream);
    fill_buckets<<<nbf, 256, 0, stream>>>(adj_row, adj_col, adj_val, n_edges,
                                          gcount, pairA);
    bucket_sort<<<NBUK, 256, 0, stream>>>(pairA, pairB, gcount, rs);

    // --- bf16 copy of layer-0 table ---
    {
        int n4 = N_TOTAL * 16;
        convert_emb<<<(n4 + 255) / 256, 256, 0, stream>>>(
            (const float4*)node_emb, emb0h, n4);
    }

    // --- acc init (layer-0, fp32 exact) ---
    {
        int threads = 2 * batch * 16;
        gather_init<<<(threads + 255) / 256, 256, 0, stream>>>(
            (const float4*)node_emb, user_ids, item_ids, (float4*)acc, batch);
    }

    const int rblocks = ((N_TOTAL * 16) + 255) / 256;
    const int gblocks = ((2 * batch * 16) + 255) / 256;

    // layer 1
    spmm_bf16<<<rblocks, 256, 0, stream>>>(emb0h, rs, pairB, bufAh);
    acc_gather_add_h<<<gblocks, 256, 0, stream>>>(bufAh, user_ids, item_ids,
                                                  (float4*)acc, batch);
    // layer 2
    spmm_bf16<<<rblocks, 256, 0, stream>>>(bufAh, rs, pairB, bufBh);
    acc_gather_add_h<<<gblocks, 256, 0, stream>>>(bufBh, user_ids, item_ids,
                                                  (float4*)acc, batch);
    // layer 3: only the 2*batch rows we actually read
    spmm_rows_acc<<<gblocks, 256, 0, stream>>>(bufBh, rs, pairB, user_ids,
                                               item_ids, (float4*)acc, batch);

    // readout
    {
        int threads = batch * 16;
        final_dot<<<(threads + 255) / 256, 256, 0, stream>>>((const float4*)acc, out, batch);
    }
}

// Round 11
// 310.361 us; speedup vs baseline: 1.0772x; 1.0772x over previous
//
#include <hip/hip_runtime.h>

#define N_TOTAL    150100
#define NUM_USERS  100000
#define DIM        64
#define BSHIFT     8                                   // 256 rows per bucket
#define BROWS      (1 << BSHIFT)
#define NBUK       ((N_TOTAL + BROWS - 1) / BROWS)     // 587
#define EPB        4096                                // edges per build block
#define CAP        5632                                // bucket capacity (mu=5116, sigma=72)
#define RSP        260                                 // row_start pitch (257 used)

// ---------- bf16 helpers (round-to-nearest-even, pack 2 per uint) ----------
__device__ __forceinline__ unsigned bfr(float f) {
    unsigned u = __float_as_uint(f);
    return (u + 0x7FFFu + ((u >> 16) & 1u)) >> 16;
}
__device__ __forceinline__ unsigned pack2(float lo, float hi) {
    return bfr(lo) | (bfr(hi) << 16);
}
__device__ __forceinline__ float unlo(unsigned w) { return __uint_as_float(w << 16); }
__device__ __forceinline__ float unhi(unsigned w) { return __uint_as_float(w & 0xFFFF0000u); }

// fp32 table -> bf16 table; also zeros gcount (saves a memset launch; this
// kernel is stream-ordered before fill_buckets).
__global__ void convert_emb(const float4* __restrict__ in4,
                            uint2* __restrict__ outh, int n4,
                            int* __restrict__ gcount) {
    int t = blockIdx.x * blockDim.x + threadIdx.x;
    if (t < NBUK) gcount[t] = 0;
    if (t >= n4) return;
    float4 f = in4[t];
    outh[t] = make_uint2(pack2(f.x, f.y), pack2(f.z, f.w));
}

// ---------- build stage 1: LDS-staged bucket fill, coalesced run writes ------
__global__ void __launch_bounds__(256) fill_buckets(
        const int* __restrict__ rows, const int* __restrict__ cols,
        const float* __restrict__ vals, int n_edges,
        int* __restrict__ gcount, int2* __restrict__ pair) {
    __shared__ int2  buf[EPB];       // 32 KB (sorted-by-bucket staging)
    __shared__ short tgtb[EPB];      // 8 KB (bucket id per sorted slot)
    __shared__ int   hist[NBUK];
    __shared__ int   pref[NBUK];
    __shared__ int   loc[NBUK];
    __shared__ int   scan[256];
    const int tid = threadIdx.x;
    const int base = blockIdx.x * EPB;
    int end = base + EPB; if (end > n_edges) end = n_edges;
    const int cnt = end - base;

    for (int i = tid; i < NBUK; i += 256) hist[i] = 0;
    __syncthreads();
    // pass 1: LDS histogram of bucket ids
    for (int i = base + tid; i < end; i += 256)
        atomicAdd(&hist[rows[i] >> BSHIFT], 1);
    __syncthreads();
    // prefix scan over NBUK bins (3 bins/thread + block scan)
    const int t0 = tid * 3;
    int t1 = t0 + 3; if (t1 > NBUK) t1 = NBUK;
    int s = 0;
    for (int i = t0; i < t1; ++i) s += hist[i];
    scan[tid] = s;
    __syncthreads();
    for (int off = 1; off < 256; off <<= 1) {
        int v = 0;
        if (tid >= off) v = scan[tid - off];
        __syncthreads();
        if (tid >= off) scan[tid] += v;
        __syncthreads();
    }
    int run = (tid == 0) ? 0 : scan[tid - 1];
    for (int i = t0; i < t1; ++i) { int h = hist[i]; pref[i] = run; run += h; }
    __syncthreads();
    // global run reservations (1 atomic per nonzero (block,bucket))
    for (int b = tid; b < NBUK; b += 256) {
        int h = hist[b];
        loc[b] = h ? (b * CAP + atomicAdd(&gcount[b], h)) : 0;
        hist[b] = pref[b];           // reuse as LDS cursor
    }
    __syncthreads();
    // pass 2: re-read edges (L2-hot), scatter into LDS sorted-by-bucket order
    for (int i = base + tid; i < end; i += 256) {
        int r = rows[i];
        int b = r >> BSHIFT;
        int pos = atomicAdd(&hist[b], 1);
        buf[pos] = make_int2(((r & (BROWS - 1)) << 18) | cols[i],
                             __float_as_int(vals[i]));
        tgtb[pos] = (short)b;
    }
    __syncthreads();
    // pass 3: coalesced run writes (target recomputed from bucket id)
    for (int i = tid; i < cnt; i += 256) {
        int b = tgtb[i];
        int t = loc[b] + (i - pref[b]);
        if (t < NBUK * CAP)          // statistically unreachable overflow guard
            pair[t] = buf[i];
    }
}

// ---------- build stage 2: per-bucket counting sort (in-place, LDS-staged) ---
__global__ void __launch_bounds__(256) bucket_sort(
        int2* __restrict__ pair,
        const int* __restrict__ gcount,
        int* __restrict__ rs) {
    __shared__ int2 buf[CAP];      // 45 KB
    __shared__ int hist[BROWS];
    __shared__ int pref[BROWS];
    const int tid = threadIdx.x;
    const int b = blockIdx.x;
    const int k0 = b * CAP;
    int cnt = gcount[b]; if (cnt > CAP) cnt = CAP;

    hist[tid] = 0;
    __syncthreads();
    for (int i = tid; i < cnt; i += 256) {
        int2 e = pair[k0 + i];
        buf[i] = e;
        atomicAdd(&hist[e.x >> 18], 1);
    }
    __syncthreads();
    pref[tid] = hist[tid];
    __syncthreads();
    #pragma unroll
    for (int off = 1; off < BROWS; off <<= 1) {
        int v = 0;
        if (tid >= off) v = pref[tid - off];
        __syncthreads();
        if (tid >= off) pref[tid] += v;
        __syncthreads();
    }
    const int rbase = b << BSHIFT;
    int nrow = N_TOTAL - rbase; if (nrow > BROWS) nrow = BROWS;
    if (tid < nrow) {
        int ex = pref[tid] - hist[tid];
        rs[b * RSP + tid] = k0 + ex;
        hist[tid] = ex;                  // reuse as local cursor
    }
    if (tid == 0) rs[b * RSP + nrow] = k0 + cnt;
    __syncthreads();
    for (int i = tid; i < cnt; i += 256) {
        int2 e = buf[i];
        int rl = e.x >> 18;
        int pos = atomicAdd(&hist[rl], 1);
        pair[k0 + pos] = make_int2(e.x & 0x3FFFF, e.y);   // strip row bits
    }
}

// ---------- propagation: bf16 gather, 16 lanes/row, 4-edge load batching ----

#define SPMM_BODY(C, V)                                                        \
    do {                                                                       \
        uint2 w = embh[(size_t)(C) * 16 + sl];                                 \
        s.x += (V) * unlo(w.x); s.y += (V) * unhi(w.x);                        \
        s.z += (V) * unlo(w.y); s.w += (V) * unhi(w.y);                        \
    } while (0)

__global__ void spmm_bf16(const uint2* __restrict__ embh,
                          const int* __restrict__ rs,
                          const int2* __restrict__ pair,
                          uint2* __restrict__ outh) {
    int t = blockIdx.x * blockDim.x + threadIdx.x;
    int r = t >> 4;
    int sl = t & 15;
    int lane = threadIdx.x & 63;
    int subbase = lane & 48;
    if (r >= N_TOTAL) return;
    const int* rsb = rs + (r >> BSHIFT) * RSP + (r & (BROWS - 1));
    int k0 = rsb[0], k1 = rsb[1];
    float4 s = make_float4(0.f, 0.f, 0.f, 0.f);
    for (int kb = k0; kb < k1; kb += 16) {
        int cnt = k1 - kb; if (cnt > 16) cnt = 16;
        int2 pr = (sl < cnt) ? pair[kb + sl] : make_int2(0, 0);
        int j = 0;
        for (; j + 4 <= cnt; j += 4) {
            int   c0 = __shfl(pr.x, subbase + j + 0, 64);
            int   c1 = __shfl(pr.x, subbase + j + 1, 64);
            int   c2 = __shfl(pr.x, subbase + j + 2, 64);
            int   c3 = __shfl(pr.x, subbase + j + 3, 64);
            float v0 = __int_as_float(__shfl(pr.y, subbase + j + 0, 64));
            float v1 = __int_as_float(__shfl(pr.y, subbase + j + 1, 64));
            float v2 = __int_as_float(__shfl(pr.y, subbase + j + 2, 64));
            float v3 = __int_as_float(__shfl(pr.y, subbase + j + 3, 64));
            uint2 w0 = embh[(size_t)c0 * 16 + sl];
            uint2 w1 = embh[(size_t)c1 * 16 + sl];
            uint2 w2 = embh[(size_t)c2 * 16 + sl];
            uint2 w3 = embh[(size_t)c3 * 16 + sl];
            s.x += v0 * unlo(w0.x); s.y += v0 * unhi(w0.x);
            s.z += v0 * unlo(w0.y); s.w += v0 * unhi(w0.y);
            s.x += v1 * unlo(w1.x); s.y += v1 * unhi(w1.x);
            s.z += v1 * unlo(w1.y); s.w += v1 * unhi(w1.y);
            s.x += v2 * unlo(w2.x); s.y += v2 * unhi(w2.x);
            s.z += v2 * unlo(w2.y); s.w += v2 * unhi(w2.y);
            s.x += v3 * unlo(w3.x); s.y += v3 * unhi(w3.x);
            s.z += v3 * unlo(w3.y); s.w += v3 * unhi(w3.y);
        }
        for (; j < cnt; ++j) {
            int   c = __shfl(pr.x, subbase + j, 64);
            float v = __int_as_float(__shfl(pr.y, subbase + j, 64));
            SPMM_BODY(c, v);
        }
    }
    outh[(size_t)r * 16 + sl] = make_uint2(pack2(s.x, s.y), pack2(s.z, s.w));
}

// Layer-3: row-sum only at the 2*batch gathered rows, write fp32 l3buf
__global__ void spmm_rows(const uint2* __restrict__ embh,
                          const int* __restrict__ rs,
                          const int2* __restrict__ pair,
                          const int* __restrict__ user_ids,
                          const int* __restrict__ item_ids,
                          float4* __restrict__ l3, int batch) {
    int t = blockIdx.x * blockDim.x + threadIdx.x;
    int b = t >> 4;
    int sl = t & 15;
    int lane = threadIdx.x & 63;
    int subbase = lane & 48;
    if (b >= 2 * batch) return;
    int r = (b < batch) ? user_ids[b] : (NUM_USERS + item_ids[b - batch]);
    const int* rsb = rs + (r >> BSHIFT) * RSP + (r & (BROWS - 1));
    int k0 = rsb[0], k1 = rsb[1];
    float4 s = make_float4(0.f, 0.f, 0.f, 0.f);
    for (int kb = k0; kb < k1; kb += 16) {
        int cnt = k1 - kb; if (cnt > 16) cnt = 16;
        int2 pr = (sl < cnt) ? pair[kb + sl] : make_int2(0, 0);
        for (int j = 0; j < cnt; ++j) {
            int   c = __shfl(pr.x, subbase + j, 64);
            float v = __int_as_float(__shfl(pr.y, subbase + j, 64));
            SPMM_BODY(c, v);
        }
    }
    l3[(size_t)b * 16 + sl] = s;
}

// ---------- fused readout: gather node_emb + A + B + l3, dot, reduce ----------
__global__ void final_dot_fused(const float4* __restrict__ emb4,
                                const uint2* __restrict__ A,
                                const uint2* __restrict__ B,
                                const float4* __restrict__ l3,
                                const int* __restrict__ user_ids,
                                const int* __restrict__ item_ids,
                                float* __restrict__ out, int batch) {
    int t = blockIdx.x * blockDim.x + threadIdx.x;
    int b = t >> 4, sl = t & 15;
    if (b >= batch) return;
    int u = user_ids[b];
    int iN = NUM_USERS + item_ids[b];

    float4 nu = emb4[(size_t)u * 16 + sl];
    uint2  au = A[(size_t)u * 16 + sl];
    uint2  bu = B[(size_t)u * 16 + sl];
    float4 lu = l3[(size_t)b * 16 + sl];
    float4 ni = emb4[(size_t)iN * 16 + sl];
    uint2  ai = A[(size_t)iN * 16 + sl];
    uint2  bi = B[(size_t)iN * 16 + sl];
    float4 li = l3[(size_t)(b + batch) * 16 + sl];

    float ux = nu.x + unlo(au.x) + unlo(bu.x) + lu.x;
    float uy = nu.y + unhi(au.x) + unhi(bu.x) + lu.y;
    float uz = nu.z + unlo(au.y) + unlo(bu.y) + lu.z;
    float uw = nu.w + unhi(au.y) + unhi(bu.y) + lu.w;
    float ix = ni.x + unlo(ai.x) + unlo(bi.x) + li.x;
    float iy = ni.y + unhi(ai.x) + unhi(bi.x) + li.y;
    float iz = ni.z + unlo(ai.y) + unlo(bi.y) + li.z;
    float iw = ni.w + unhi(ai.y) + unhi(bi.y) + li.w;

    float s = ux * ix + uy * iy + uz * iz + uw * iw;
    #pragma unroll
    for (int off = 8; off > 0; off >>= 1) s += __shfl_down(s, off, 64);
    if (sl == 0) out[b] = s * (1.0f / 16.0f);
}

// ---------- launch ----------

static inline size_t align256(size_t x) { return (x + 255) & ~(size_t)255; }

extern "C" void kernel_launch(void* const* d_in, const int* in_sizes, int n_in,
                              void* d_out, int out_size, void* d_ws, size_t ws_size,
                              hipStream_t stream) {
    const float* node_emb = (const float*)d_in[0];
    const float* adj_val  = (const float*)d_in[1];
    const int*   adj_row  = (const int*)d_in[2];
    const int*   adj_col  = (const int*)d_in[3];
    const int*   user_ids = (const int*)d_in[4];
    const int*   item_ids = (const int*)d_in[5];
    float* out = (float*)d_out;

    const int n_edges = in_sizes[1];
    const int batch   = in_sizes[4];

    const size_t embh_bytes = (size_t)N_TOTAL * DIM * 2;   // bf16 table

    char* p = (char*)d_ws;
    size_t off = 0;
    uint2* emb0h  = (uint2*)(p + off); off = align256(off + embh_bytes);
    uint2* bufAh  = (uint2*)(p + off); off = align256(off + embh_bytes);
    uint2* bufBh  = (uint2*)(p + off); off = align256(off + embh_bytes);
    float* l3buf  = (float*)(p + off); off = align256(off + (size_t)2 * batch * DIM * sizeof(float));
    int* gcount   = (int*)(p + off);   off = align256(off + (size_t)NBUK * sizeof(int));
    int* rs       = (int*)(p + off);   off = align256(off + (size_t)NBUK * RSP * sizeof(int));
    int2* pairA   = (int2*)(p + off);  off = align256(off + (size_t)NBUK * CAP * sizeof(int2));
    (void)ws_size;

    const int nbf = (n_edges + EPB - 1) / EPB;   // 733

    // --- bf16 table conversion (also zeros gcount, stream-ordered first) ---
    {
        int n4 = N_TOTAL * 16;
        convert_emb<<<(n4 + 255) / 256, 256, 0, stream>>>(
            (const float4*)node_emb, emb0h, n4, gcount);
    }

    // --- build ---
    fill_buckets<<<nbf, 256, 0, stream>>>(adj_row, adj_col, adj_val, n_edges,
                                          gcount, pairA);
    bucket_sort<<<NBUK, 256, 0, stream>>>(pairA, gcount, rs);

    const int rblocks = ((N_TOTAL * 16) + 255) / 256;
    const int gblocks = ((2 * batch * 16) + 255) / 256;

    // layer 1, layer 2 (full table), layer 3 (gathered rows only)
    spmm_bf16<<<rblocks, 256, 0, stream>>>(emb0h, rs, pairA, bufAh);
    spmm_bf16<<<rblocks, 256, 0, stream>>>(bufAh, rs, pairA, bufBh);
    spmm_rows<<<gblocks, 256, 0, stream>>>(bufBh, rs, pairA, user_ids,
                                           item_ids, (float4*)l3buf, batch);

    // fused readout: (node_emb + A + B + l3) dot
    {
        int threads = batch * 16;
        final_dot_fused<<<(threads + 255) / 256, 256, 0, stream>>>(
            (const float4*)node_emb, bufAh, bufBh, (const float4*)l3buf,
            user_ids, item_ids, out, batch);
    }
}